// Round 4
// baseline (109.278 us; speedup 1.0000x reference)
//
#include <hip/hip_runtime.h>
#include <hip/hip_bf16.h>

// Fully fused NCC loss. Per block: one 32x32 (h,w) core tile x one 19-deep
// d-segment. March 27 slices (19 outputs + 8 halo):
//   A: stage 40x40 f32 (f,w) slice tile -> LDS (float2)
//   B: W-direction 9-tap sums (incremental by 4) -> tp f32
//   C: H-direction 9-tap sums (incremental by 4) -> hw bf16-packed
//   D: per-voxel register ring (5ch x 9, slot = p%9 compile-time via
//      outer x unroll-9) + running D-sums + ncc accumulate (fp32).
// No global intermediates: HBM = input reads + 450 partials.

constexpr int BB = 2, DD = 160, WW = 160;
constexpr int SLICE = 160 * 160;                         // 25600
constexpr long long NTOT = (long long)BB * DD * SLICE;   // 8,192,000
constexpr int DSEG = 19, NSEG = 9, NBLK = 25 * NSEG * BB; // 450 blocks

static __device__ __forceinline__ uint packbf(float x, float y) {
  __hip_bfloat16 hx = __float2bfloat16(x), hy = __float2bfloat16(y);
  ushort ux = *reinterpret_cast<ushort*>(&hx);
  ushort uy = *reinterpret_cast<ushort*>(&hy);
  return (uint)ux | ((uint)uy << 16);
}
static __device__ __forceinline__ float lof(uint u) { return __uint_as_float(u << 16); }
static __device__ __forceinline__ float hif(uint u) { return __uint_as_float(u & 0xFFFF0000u); }

__global__ __launch_bounds__(1024) void ncc_fused_kernel(
    const float* __restrict__ f, const float* __restrict__ w,
    float* __restrict__ partials) {
  __shared__ float2 sfw[40][42];        // staged slice (f,w), 13.44 KB
  __shared__ float tp[40][33][6];       // W-sums f32, 31.68 KB (stride 198 words)
  __shared__ uint2 hw01[32][33];        // HW-sums ch0..3 bf16-packed, 8.45 KB
  __shared__ uint hw4[32][33];          // HW-sums ch4, 4.22 KB   (total 57.8 KB)

  const int t = threadIdx.x;
  const int tile = blockIdx.x;                 // 0..24
  const int h0 = (tile / 5) * 32, w0 = (tile % 5) * 32;
  const int seg = blockIdx.y;                  // 0..8
  const int b = blockIdx.z;
  const int jb = seg * DSEG - 4;               // first staged slice index
  const float* fb = f + (long long)b * DD * SLICE;
  const float* wb = w + (long long)b * DD * SLICE;

  // ---- per-phase thread assignments (fixed across d-steps) ----
  // A: t<400 : 40 rows x 10 float4-groups, both volumes
  const int rA = t / 10, gA = t % 10;
  const int hA = h0 - 4 + rA, xA = w0 - 4 + 4 * gA;
  const bool vA = (t < 400) && ((unsigned)hA < 160u) && ((unsigned)xA < 160u);
  const int offA = hA * WW + xA;
  // B: t<320 : 40 rows x 8 col-groups of 4
  const int rB = t >> 3, cB = (t & 7) * 4;
  // C: t<256 : 8 row-groups of 4 x 32 cols
  const int r0C = (t >> 5) * 4, cC = t & 31;
  // D: all 1024 : one voxel
  const int rD = t >> 5, cD = t & 31;

  float ring[5][9];
#pragma unroll
  for (int ch = 0; ch < 5; ++ch)
#pragma unroll
    for (int k = 0; k < 9; ++k) ring[ch][k] = 0.f;
  float S0 = 0.f, S1 = 0.f, S2 = 0.f, S3 = 0.f, S4 = 0.f, acc = 0.f;
  const float inv = 1.0f / 729.0f;

  // ---- prologue: stage slice jb ----
  {
    float4 vf = make_float4(0.f, 0.f, 0.f, 0.f);
    float4 vw = make_float4(0.f, 0.f, 0.f, 0.f);
    if (vA && (unsigned)jb < 160u) {
      const long long o = (long long)jb * SLICE + offA;
      vf = *reinterpret_cast<const float4*>(fb + o);
      vw = *reinterpret_cast<const float4*>(wb + o);
    }
    if (t < 400) {
      float4 lo = make_float4(vf.x, vw.x, vf.y, vw.y);
      float4 hi = make_float4(vf.z, vw.z, vf.w, vw.w);
      *reinterpret_cast<float4*>(&sfw[rA][4 * gA]) = lo;
      *reinterpret_cast<float4*>(&sfw[rA][4 * gA + 2]) = hi;
    }
  }

  for (int m = 0; m < 3; ++m) {
#pragma unroll
    for (int q = 0; q < 9; ++q) {
      const int p = m * 9 + q;
      __syncthreads();   // sfw(p) staged; hw consumed by previous D

      // ---- B: W-direction sums ----
      if (t < 320) {
        float a0 = 0.f, a1 = 0.f, a2 = 0.f, a3 = 0.f, a4 = 0.f;
#pragma unroll
        for (int k = 0; k < 9; ++k) {
          const float2 v = sfw[rB][cB + k];
          a0 += v.x; a1 += v.y;
          a2 += v.x * v.x; a3 += v.y * v.y; a4 += v.x * v.y;
        }
        float* tr = &tp[rB][cB][0];
        *reinterpret_cast<float2*>(tr) = make_float2(a0, a1);
        *reinterpret_cast<float2*>(tr + 2) = make_float2(a2, a3);
        tr[4] = a4;
#pragma unroll
        for (int j = 1; j < 4; ++j) {
          const float2 vn = sfw[rB][cB + 8 + j];
          const float2 vo = sfw[rB][cB + j - 1];
          a0 += vn.x - vo.x; a1 += vn.y - vo.y;
          a2 += vn.x * vn.x - vo.x * vo.x;
          a3 += vn.y * vn.y - vo.y * vo.y;
          a4 += vn.x * vn.y - vo.x * vo.y;
          float* tw = &tp[rB][cB + j][0];
          *reinterpret_cast<float2*>(tw) = make_float2(a0, a1);
          *reinterpret_cast<float2*>(tw + 2) = make_float2(a2, a3);
          tw[4] = a4;
        }
      }
      __syncthreads();   // tp ready; sfw free

      // ---- A: stage next slice (overlaps with C/D compute) ----
      if (p < 26) {
        const int j2 = jb + p + 1;
        float4 vf = make_float4(0.f, 0.f, 0.f, 0.f);
        float4 vw = make_float4(0.f, 0.f, 0.f, 0.f);
        if (vA && (unsigned)j2 < 160u) {
          const long long o = (long long)j2 * SLICE + offA;
          vf = *reinterpret_cast<const float4*>(fb + o);
          vw = *reinterpret_cast<const float4*>(wb + o);
        }
        if (t < 400) {
          float4 lo = make_float4(vf.x, vw.x, vf.y, vw.y);
          float4 hi = make_float4(vf.z, vw.z, vf.w, vw.w);
          *reinterpret_cast<float4*>(&sfw[rA][4 * gA]) = lo;
          *reinterpret_cast<float4*>(&sfw[rA][4 * gA + 2]) = hi;
        }
      }

      // ---- C: H-direction sums -> bf16-packed hw ----
      if (t < 256) {
        float s0 = 0.f, s1 = 0.f, s2 = 0.f, s3 = 0.f, s4 = 0.f;
#pragma unroll
        for (int k = 0; k < 9; ++k) {
          const float* tr = &tp[r0C + k][cC][0];
          const float2 p01 = *reinterpret_cast<const float2*>(tr);
          const float2 p23 = *reinterpret_cast<const float2*>(tr + 2);
          s0 += p01.x; s1 += p01.y; s2 += p23.x; s3 += p23.y; s4 += tr[4];
        }
        hw01[r0C][cC] = make_uint2(packbf(s0, s1), packbf(s2, s3));
        hw4[r0C][cC] = packbf(s4, 0.f);
#pragma unroll
        for (int j = 1; j < 4; ++j) {
          const float* to = &tp[r0C + j - 1][cC][0];
          const float* tn = &tp[r0C + j + 8][cC][0];
          const float2 o01 = *reinterpret_cast<const float2*>(to);
          const float2 o23 = *reinterpret_cast<const float2*>(to + 2);
          const float2 n01 = *reinterpret_cast<const float2*>(tn);
          const float2 n23 = *reinterpret_cast<const float2*>(tn + 2);
          s0 += n01.x - o01.x; s1 += n01.y - o01.y;
          s2 += n23.x - o23.x; s3 += n23.y - o23.y;
          s4 += tn[4] - to[4];
          hw01[r0C + j][cC] = make_uint2(packbf(s0, s1), packbf(s2, s3));
          hw4[r0C + j][cC] = packbf(s4, 0.f);
        }
      }
      __syncthreads();   // hw ready

      // ---- D: ring update + ncc ----
      {
        const uint2 u = hw01[rD][cD];
        const float n0 = lof(u.x), n1 = hif(u.x);
        const float n2 = lof(u.y), n3 = hif(u.y);
        const float n4 = lof(hw4[rD][cD]);
        S0 += n0 - ring[0][q]; ring[0][q] = n0;
        S1 += n1 - ring[1][q]; ring[1][q] = n1;
        S2 += n2 - ring[2][q]; ring[2][q] = n2;
        S3 += n3 - ring[3][q]; ring[3][q] = n3;
        S4 += n4 - ring[4][q]; ring[4][q] = n4;
        const int d = seg * DSEG + p - 8;
        if (p >= 8 && d < 160) {
          const float fm = S0 * inv, wm = S1 * inv;
          const float fsq = S2 * inv, wsq = S3 * inv, fw = S4 * inv;
          const float fv = fsq - fm * fm;
          const float wv = wsq - wm * wm;
          const float cov = fw - fm * wm;
          const float den = sqrtf(fmaxf(fv, 0.f) + 1e-8f) *
                            sqrtf(fmaxf(wv, 0.f) + 1e-8f);
          acc += fminf(1.f, fmaxf(-1.f, cov / den));
        }
      }
    }
  }

  // ---- block reduction (reuse tp as scratch) ----
  __syncthreads();
  float* red = reinterpret_cast<float*>(tp);
  red[t] = acc;
  __syncthreads();
#pragma unroll
  for (int st = 512; st > 0; st >>= 1) {
    if (t < st) red[t] += red[t + st];
    __syncthreads();
  }
  if (t == 0)
    partials[(blockIdx.z * NSEG + blockIdx.y) * 25 + blockIdx.x] = red[0];
}

__global__ __launch_bounds__(512) void ncc_final_kernel(
    const float* __restrict__ partials, float* __restrict__ out) {
  __shared__ float red[512];
  const int t = threadIdx.x;
  red[t] = (t < NBLK) ? partials[t] : 0.f;
  __syncthreads();
#pragma unroll
  for (int st = 256; st > 0; st >>= 1) {
    if (t < st) red[t] += red[t + st];
    __syncthreads();
  }
  if (t == 0) out[0] = -red[0] * (1.0f / (float)NTOT);
}

extern "C" void kernel_launch(void* const* d_in, const int* in_sizes, int n_in,
                              void* d_out, int out_size, void* d_ws, size_t ws_size,
                              hipStream_t stream) {
  const float* fixed = (const float*)d_in[0];
  const float* warped = (const float*)d_in[1];
  float* out = (float*)d_out;
  float* partials = (float*)d_ws;     // 450 floats

  dim3 gf(25, NSEG, BB);              // 450 blocks x 1024 threads
  ncc_fused_kernel<<<gf, dim3(1024), 0, stream>>>(fixed, warped, partials);
  ncc_final_kernel<<<1, dim3(512), 0, stream>>>(partials, out);
}

// Round 5
// 104.640 us; speedup vs baseline: 1.0443x; 1.0443x over previous
//
#include <hip/hip_runtime.h>
#include <hip/hip_fp16.h>

// NCC loss, D-first separable order.
// K_d : thread-per-(h,w)-column marches D with 5x9 register ring (static
//       slots via full unroll). Reads f,w once (coalesced), no LDS, no
//       barriers. Writes 5 D-window sums fp16-packed (uint2 + uint, 12B/vox).
// K_hw: per d-slice 32x32 tile: stage packed sums -> W 9-tap (incremental)
//       -> f32 planar tp (conflict-free) -> H 9-tap (incremental) -> ncc ->
//       in-register reduction. No global writes except 1 partial per block.
// K_f : deterministic final reduction.

constexpr int BB = 2, DD = 160, WW = 160;
constexpr int SLICE = 160 * 160;                        // 25600
constexpr long long NTOT = (long long)BB * DD * SLICE;  // 8,192,000
constexpr int DSEG = 20, NSEGD = 8;                     // K_d: 8 segs of 20
constexpr int NBLK_HW = 25 * DD * BB;                   // 8000 partials

static __device__ __forceinline__ unsigned pkh(float a, float b) {
  __half2 h = __floats2half2_rn(a, b);
  return __builtin_bit_cast(unsigned, h);
}
static __device__ __forceinline__ float2 uph(unsigned u) {
  __half2 h = __builtin_bit_cast(__half2, u);
  return __half22float2(h);
}

// ---------------- K_d: D-axis window sums, pure stream ----------------
__global__ __launch_bounds__(256) void ncc_d_kernel(
    const float* __restrict__ f, const float* __restrict__ w,
    uint2* __restrict__ o01, unsigned* __restrict__ o4) {
  const int tid = threadIdx.x;
  const int col = blockIdx.x * 256 + tid;   // 0..51199
  const int b = col / SLICE;
  const int r = col % SLICE;
  const int d0 = blockIdx.y * DSEG;
  const long long base = (long long)b * DD * SLICE + r;
  const float* fb = f + base;
  const float* wb = w + base;

  float rf[9], rw[9], rf2[9], rw2[9], rfw[9];
#pragma unroll
  for (int k = 0; k < 9; ++k) { rf[k] = rw[k] = rf2[k] = rw2[k] = rfw[k] = 0.f; }
  float S0 = 0.f, S1 = 0.f, S2 = 0.f, S3 = 0.f, S4 = 0.f;

#pragma unroll
  for (int p = 0; p < DSEG + 8; ++p) {      // 28 steps
    const int j = d0 - 4 + p;               // block-uniform guard
    float vf = 0.f, vw = 0.f;
    if ((unsigned)j < 160u) {
      vf = fb[(long long)j * SLICE];
      vw = wb[(long long)j * SLICE];
    }
    const float a2 = vf * vf, a3 = vw * vw, a4 = vf * vw;
    const int sl = p % 9;                   // compile-time after unroll
    S0 += vf - rf[sl];  rf[sl] = vf;
    S1 += vw - rw[sl];  rw[sl] = vw;
    S2 += a2 - rf2[sl]; rf2[sl] = a2;
    S3 += a3 - rw2[sl]; rw2[sl] = a3;
    S4 += a4 - rfw[sl]; rfw[sl] = a4;
    if (p >= 8) {
      const long long v = base + (long long)(d0 + p - 8) * SLICE;
      o01[v] = make_uint2(pkh(S0, S1), pkh(S2, S3));
      o4[v] = pkh(S4, 0.f);
    }
  }
}

static __device__ __forceinline__ float nccv(float S0, float S1, float S2,
                                             float S3, float S4) {
  const float inv = 1.0f / 729.0f;
  const float fm = S0 * inv, wm = S1 * inv;
  const float fv = S2 * inv - fm * fm;
  const float wv = S3 * inv - wm * wm;
  const float cov = S4 * inv - fm * wm;
  const float den = sqrtf(fmaxf(fv, 0.f) + 1e-8f) * sqrtf(fmaxf(wv, 0.f) + 1e-8f);
  return fminf(1.f, fmaxf(-1.f, cov / den));
}

// ---------------- K_hw: W+H window sums + ncc, tiled ----------------
__global__ __launch_bounds__(256) void ncc_hw_kernel(
    const uint2* __restrict__ i01, const unsigned* __restrict__ i4,
    float* __restrict__ partials) {
  __shared__ uint2 s01[40][41];      // 13.12 KB
  __shared__ unsigned s4[40][41];    //  6.56 KB
  __shared__ float tp[5][40][33];    // 26.40 KB (planar: conflict-free)

  const int t = threadIdx.x;
  const int tile = blockIdx.x;                 // 0..24
  const int h0 = (tile / 5) * 32, w0 = (tile % 5) * 32;
  const int d = blockIdx.y, b = blockIdx.z;
  const long long sbase = (long long)(b * DD + d) * SLICE;

  // ---- stage 40x40 packed tile ----
  for (int i = t; i < 1600; i += 256) {
    const int r = i / 40, c = i % 40;
    const int h = h0 - 4 + r, x = w0 - 4 + c;
    uint2 v01 = make_uint2(0u, 0u);
    unsigned v4 = 0u;
    if ((unsigned)h < 160u && (unsigned)x < 160u) {
      const long long g = sbase + h * WW + x;
      v01 = i01[g];
      v4 = i4[g];
    }
    s01[r][c] = v01;
    s4[r][c] = v4;
  }
  __syncthreads();

  // ---- W-direction 9-tap sums (incremental by 4): 40 rows x 8 groups ----
  for (int g = t; g < 320; g += 256) {
    const int r = g >> 3, c0 = (g & 7) * 4;
    float a0 = 0.f, a1 = 0.f, a2 = 0.f, a3 = 0.f, a4 = 0.f;
#pragma unroll
    for (int k = 0; k < 9; ++k) {
      const uint2 u = s01[r][c0 + k];
      const float2 p01 = uph(u.x), p23 = uph(u.y);
      const float2 p4 = uph(s4[r][c0 + k]);
      a0 += p01.x; a1 += p01.y; a2 += p23.x; a3 += p23.y; a4 += p4.x;
    }
    tp[0][r][c0] = a0; tp[1][r][c0] = a1; tp[2][r][c0] = a2;
    tp[3][r][c0] = a3; tp[4][r][c0] = a4;
#pragma unroll
    for (int j = 1; j < 4; ++j) {
      const uint2 un = s01[r][c0 + 8 + j], uo = s01[r][c0 + j - 1];
      const float2 n01 = uph(un.x), n23 = uph(un.y);
      const float2 o01v = uph(uo.x), o23 = uph(uo.y);
      const float2 n4 = uph(s4[r][c0 + 8 + j]), o4v = uph(s4[r][c0 + j - 1]);
      a0 += n01.x - o01v.x; a1 += n01.y - o01v.y;
      a2 += n23.x - o23.x;  a3 += n23.y - o23.y;
      a4 += n4.x - o4v.x;
      tp[0][r][c0 + j] = a0; tp[1][r][c0 + j] = a1; tp[2][r][c0 + j] = a2;
      tp[3][r][c0 + j] = a3; tp[4][r][c0 + j] = a4;
    }
  }
  __syncthreads();

  // ---- H-direction 9-tap (incremental by 4) + ncc: 8 rgroups x 32 cols ----
  float acc = 0.f;
  {
    const int c = t & 31, r0 = (t >> 5) * 4;
    float s0 = 0.f, s1 = 0.f, s2 = 0.f, s3 = 0.f, s4v = 0.f;
#pragma unroll
    for (int k = 0; k < 9; ++k) {
      s0 += tp[0][r0 + k][c]; s1 += tp[1][r0 + k][c]; s2 += tp[2][r0 + k][c];
      s3 += tp[3][r0 + k][c]; s4v += tp[4][r0 + k][c];
    }
    acc += nccv(s0, s1, s2, s3, s4v);
#pragma unroll
    for (int j = 1; j < 4; ++j) {
      const int ro = r0 + j - 1, rn = r0 + j + 8;
      s0 += tp[0][rn][c] - tp[0][ro][c];
      s1 += tp[1][rn][c] - tp[1][ro][c];
      s2 += tp[2][rn][c] - tp[2][ro][c];
      s3 += tp[3][rn][c] - tp[3][ro][c];
      s4v += tp[4][rn][c] - tp[4][ro][c];
      acc += nccv(s0, s1, s2, s3, s4v);
    }
  }

  // ---- reduction: wave shuffle + tiny LDS ----
#pragma unroll
  for (int off = 32; off > 0; off >>= 1) acc += __shfl_down(acc, off, 64);
  __shared__ float wr[4];
  if ((t & 63) == 0) wr[t >> 6] = acc;
  __syncthreads();
  if (t == 0)
    partials[(long long)(b * DD + d) * 25 + tile] = wr[0] + wr[1] + wr[2] + wr[3];
}

// ---------------- K_f: final reduction ----------------
__global__ __launch_bounds__(1024) void ncc_final_kernel(
    const float* __restrict__ partials, float* __restrict__ out) {
  const int t = threadIdx.x;
  float a = 0.f;
  for (int i = t; i < NBLK_HW; i += 1024) a += partials[i];
#pragma unroll
  for (int off = 32; off > 0; off >>= 1) a += __shfl_down(a, off, 64);
  __shared__ float wr[16];
  if ((t & 63) == 0) wr[t >> 6] = a;
  __syncthreads();
  if (t == 0) {
    float s = 0.f;
#pragma unroll
    for (int k = 0; k < 16; ++k) s += wr[k];
    out[0] = -s * (1.0f / (float)NTOT);
  }
}

extern "C" void kernel_launch(void* const* d_in, const int* in_sizes, int n_in,
                              void* d_out, int out_size, void* d_ws, size_t ws_size,
                              hipStream_t stream) {
  const float* fixed = (const float*)d_in[0];
  const float* warped = (const float*)d_in[1];
  float* out = (float*)d_out;

  uint2* o01 = (uint2*)d_ws;                                        // 65.54 MB
  unsigned* o4 = (unsigned*)((char*)d_ws + (size_t)NTOT * 8);       // 32.77 MB
  float* partials = (float*)((char*)d_ws + (size_t)NTOT * 12);      // 32 KB

  dim3 gd(200, NSEGD);                 // 1600 blocks x 256
  ncc_d_kernel<<<gd, dim3(256), 0, stream>>>(fixed, warped, o01, o4);

  dim3 gh(25, DD, BB);                 // 8000 blocks x 256
  ncc_hw_kernel<<<gh, dim3(256), 0, stream>>>(o01, o4, partials);

  ncc_final_kernel<<<1, dim3(1024), 0, stream>>>(partials, out);
}